// Round 5
// baseline (244.202 us; speedup 1.0000x reference)
//
#include <hip/hip_runtime.h>
#include <cstddef>

#define N_NODES 50000
#define N_EDGES 400000
#define TOT_EDGES (N_EDGES + N_NODES)
#define M_PAD 50048    // 391 * 128  (GEMM row padding)
#define SCAN_PAD 50176 // 49 * 1024  (scan padding)

typedef _Float16 f16;
typedef __attribute__((ext_vector_type(8))) _Float16 f16x8;
typedef __attribute__((ext_vector_type(4))) _Float16 f16x4;
typedef __attribute__((ext_vector_type(2))) _Float16 f16x2;
typedef __attribute__((ext_vector_type(4))) float f32x4;

__device__ __forceinline__ int rfl(int v) { return __builtin_amdgcn_readfirstlane(v); }

// ---------------------------------------------------------------------------
// CSR build (parallel scan version)
// ---------------------------------------------------------------------------
__global__ void zero_int(int* __restrict__ p, int n) {
  int i = blockIdx.x * blockDim.x + threadIdx.x;
  if (i < n) p[i] = 0;
}

__global__ void count_kernel(const int* __restrict__ ei, int* __restrict__ cnt) {
  int e = blockIdx.x * blockDim.x + threadIdx.x;
  if (e >= TOT_EDGES) return;
  int dst = (e < N_EDGES) ? ei[N_EDGES + e] : (e - N_EDGES);
  atomicAdd(&cnt[dst], 1);
}

__global__ __launch_bounds__(256) void block_scan(const int* __restrict__ cnt,
                                                  int* __restrict__ pre,
                                                  int* __restrict__ bsum) {
  __shared__ int wsum[4];
  const int t = threadIdx.x, lane = t & 63, w = t >> 6;
  const int base = blockIdx.x * 1024 + t * 4;
  int4 v = *(const int4*)&cnt[base];
  const int s = v.x + v.y + v.z + v.w;
  int x = s;
#pragma unroll
  for (int off = 1; off < 64; off <<= 1) {
    int y = __shfl_up(x, off);
    if (lane >= off) x += y;
  }
  if (lane == 63) wsum[w] = x;
  __syncthreads();
  int woff = 0;
  for (int j = 0; j < w; ++j) woff += wsum[j];
  const int ex = x - s + woff;  // exclusive prefix within block
  pre[base + 0] = ex;
  pre[base + 1] = ex + v.x;
  pre[base + 2] = ex + v.x + v.y;
  pre[base + 3] = ex + v.x + v.y + v.z;
  if (t == 255) bsum[blockIdx.x] = ex + s;
}

__global__ void bsum_scan(int* __restrict__ bsum, int nb) {
  const int lane = threadIdx.x;
  int v = (lane < nb) ? bsum[lane] : 0;
  int x = v;
#pragma unroll
  for (int off = 1; off < 64; off <<= 1) {
    int y = __shfl_up(x, off);
    if (lane >= off) x += y;
  }
  if (lane < nb) bsum[lane] = x - v;
}

__global__ __launch_bounds__(256) void add_off(int* __restrict__ pre,
                                               const int* __restrict__ boff,
                                               int* __restrict__ cursor) {
  const int base = blockIdx.x * 1024 + threadIdx.x * 4;
  const int off = boff[blockIdx.x];
  int4 v = *(const int4*)&pre[base];
  v.x += off; v.y += off; v.z += off; v.w += off;
  *(int4*)&pre[base] = v;
  *(int4*)&cursor[base] = v;
}

__global__ void fill_kernel(const int* __restrict__ ei, int* __restrict__ cursor,
                            int* __restrict__ csr_src) {
  int e = blockIdx.x * blockDim.x + threadIdx.x;
  if (e >= TOT_EDGES) return;
  int s, d;
  if (e < N_EDGES) { s = ei[e]; d = ei[N_EDGES + e]; }
  else             { s = d = e - N_EDGES; }
  int pos = atomicAdd(&cursor[d], 1);
  csr_src[pos] = s;
}

// ---------------------------------------------------------------------------
// prep_x: x(f32) -> xb(f16, M_PAD rows, zero-padded)  +  a1 = x . V1 (f32)
// ---------------------------------------------------------------------------
__global__ __launch_bounds__(256) void prep_x(const float* __restrict__ x,
                                              f16* __restrict__ xb,
                                              const float* __restrict__ V1s,
                                              const float* __restrict__ V1d,
                                              float* __restrict__ as1,
                                              float* __restrict__ ad1) {
  const int wid = (blockIdx.x * 256 + threadIdx.x) >> 6;
  const int lane = threadIdx.x & 63;
  if (wid >= M_PAD) return;
  const int k = lane * 2;
  if (wid >= N_NODES) {
    f16x2 z; z[0] = (f16)0.f; z[1] = (f16)0.f;
    *(f16x2*)&xb[(size_t)wid * 128 + k] = z;
    return;
  }
  float2 xv = *(const float2*)&x[(size_t)wid * 128 + k];
  f16x2 o; o[0] = (f16)xv.x; o[1] = (f16)xv.y;
  *(f16x2*)&xb[(size_t)wid * 128 + k] = o;

  float4 vs0 = *(const float4*)&V1s[k * 4];
  float4 vs1 = *(const float4*)&V1s[(k + 1) * 4];
  float4 vd0 = *(const float4*)&V1d[k * 4];
  float4 vd1 = *(const float4*)&V1d[(k + 1) * 4];
  float s[4], d[4];
  s[0] = xv.x * vs0.x + xv.y * vs1.x;
  s[1] = xv.x * vs0.y + xv.y * vs1.y;
  s[2] = xv.x * vs0.z + xv.y * vs1.z;
  s[3] = xv.x * vs0.w + xv.y * vs1.w;
  d[0] = xv.x * vd0.x + xv.y * vd1.x;
  d[1] = xv.x * vd0.y + xv.y * vd1.y;
  d[2] = xv.x * vd0.z + xv.y * vd1.z;
  d[3] = xv.x * vd0.w + xv.y * vd1.w;
#pragma unroll
  for (int h = 0; h < 4; ++h) {
#pragma unroll
    for (int off = 32; off; off >>= 1) {
      s[h] += __shfl_xor(s[h], off);
      d[h] += __shfl_xor(d[h], off);
    }
  }
  if (lane == 0) {
    *(float4*)&as1[(size_t)wid * 4] = make_float4(s[0], s[1], s[2], s[3]);
    *(float4*)&ad1[(size_t)wid * 4] = make_float4(d[0], d[1], d[2], d[3]);
  }
}

// W [R][C] f32 -> Wt [C][R] f16
__global__ __launch_bounds__(256) void cvt_w_t(const float* __restrict__ W,
                                               f16* __restrict__ Wt, int R, int C) {
  int idx = blockIdx.x * 256 + threadIdx.x;
  if (idx >= R * C) return;
  int cc = idx / R, rr = idx - cc * R;
  Wt[idx] = (f16)W[(size_t)rr * C + cc];
}

__global__ __launch_bounds__(256) void make_v1(const float* __restrict__ W1,
                                               const float* __restrict__ att_s,
                                               const float* __restrict__ att_d,
                                               float* __restrict__ V1s,
                                               float* __restrict__ V1d) {
  const int wid = (blockIdx.x * 256 + threadIdx.x) >> 6;  // 0..511
  const int lane = threadIdx.x & 63;
  const int k = wid >> 2, h = wid & 3;
  const float* wrow = W1 + (size_t)k * 512 + h * 128;
  float2 wv = *(const float2*)&wrow[lane * 2];
  float2 sv = *(const float2*)&att_s[h * 128 + lane * 2];
  float2 dv = *(const float2*)&att_d[h * 128 + lane * 2];
  float ps = wv.x * sv.x + wv.y * sv.y;
  float pd = wv.x * dv.x + wv.y * dv.y;
#pragma unroll
  for (int off = 32; off; off >>= 1) {
    ps += __shfl_xor(ps, off);
    pd += __shfl_xor(pd, off);
  }
  if (lane == 0) { V1s[k * 4 + h] = ps; V1d[k * 4 + h] = pd; }
}

__global__ __launch_bounds__(256) void make_v2(const float* __restrict__ W2,
                                               const float* __restrict__ att_s,
                                               const float* __restrict__ att_d,
                                               float* __restrict__ V2s,
                                               float* __restrict__ V2d) {
  const int wid = (blockIdx.x * 256 + threadIdx.x) >> 6;  // k = 0..511
  const int lane = threadIdx.x & 63;
  const float* wrow = W2 + (size_t)wid * 128;
  float2 wv = *(const float2*)&wrow[lane * 2];
  float2 sv = *(const float2*)&att_s[lane * 2];
  float2 dv = *(const float2*)&att_d[lane * 2];
  float ps = wv.x * sv.x + wv.y * sv.y;
  float pd = wv.x * dv.x + wv.y * dv.y;
#pragma unroll
  for (int off = 32; off; off >>= 1) {
    ps += __shfl_xor(ps, off);
    pd += __shfl_xor(pd, off);
  }
  if (lane == 0) { V2s[wid] = ps; V2d[wid] = pd; }
}

// ---------------------------------------------------------------------------
// generalized MFMA GEMM: C[M_PAD][128-col tile] = A @ Bt^T, f32 accum.
// runtime lda/ldb/ldc; N tile fixed at 128 (bn = 0); grid.y = head when
// PER_HEAD (A/Bt/C/bias pre-offset per head); PER_HEAD also fuses bias+ELU.
// ---------------------------------------------------------------------------
template <int K, bool PER_HEAD>
__global__ __launch_bounds__(256) void gemm_bt(const f16* __restrict__ A, int lda,
                                               const f16* __restrict__ Bt, int ldb,
                                               f16* __restrict__ C, int ldc,
                                               const float* __restrict__ bias) {
  if constexpr (PER_HEAD) {
    const int hh = blockIdx.y;
    A += (size_t)hh * 128;
    Bt += (size_t)hh * 128 * 128;
    C += (size_t)hh * 128;
    bias += hh * 128;
  }
  constexpr int LDT = 40;
  __shared__ __align__(16) f16 As[128 * LDT];
  __shared__ __align__(16) f16 Bs[128 * LDT];
  const int tid = threadIdx.x;
  const int lane = tid & 63;
  const int g = lane >> 4, r16 = lane & 15;
  const int w = tid >> 6, wr = w >> 1, wc = w & 1;
  const long bm = (long)blockIdx.x * 128;

  const int row0 = tid >> 2, h0 = tid & 3;
  const int p1 = (h0 & 1) * 16 + (h0 >> 1) * 4;
  const size_t ga0 = (size_t)(bm + row0) * lda + h0 * 8;
  const size_t ga1 = (size_t)(bm + row0 + 64) * lda + h0 * 8;
  const size_t gb0 = (size_t)row0 * ldb + h0 * 8;
  const size_t gb1 = (size_t)(row0 + 64) * ldb + h0 * 8;
  const int la0 = row0 * LDT + p1, la1 = (row0 + 64) * LDT + p1;

  f32x4 acc[4][4] = {};

  for (int k0 = 0; k0 < K; k0 += 32) {
    __syncthreads();
    f16x8 va0 = *(const f16x8*)&A[ga0 + k0];
    f16x8 va1 = *(const f16x8*)&A[ga1 + k0];
    f16x8 vb0 = *(const f16x8*)&Bt[gb0 + k0];
    f16x8 vb1 = *(const f16x8*)&Bt[gb1 + k0];
    *(f16x4*)&As[la0]     = __builtin_shufflevector(va0, va0, 0, 1, 2, 3);
    *(f16x4*)&As[la0 + 8] = __builtin_shufflevector(va0, va0, 4, 5, 6, 7);
    *(f16x4*)&As[la1]     = __builtin_shufflevector(va1, va1, 0, 1, 2, 3);
    *(f16x4*)&As[la1 + 8] = __builtin_shufflevector(va1, va1, 4, 5, 6, 7);
    *(f16x4*)&Bs[la0]     = __builtin_shufflevector(vb0, vb0, 0, 1, 2, 3);
    *(f16x4*)&Bs[la0 + 8] = __builtin_shufflevector(vb0, vb0, 4, 5, 6, 7);
    *(f16x4*)&Bs[la1]     = __builtin_shufflevector(vb1, vb1, 0, 1, 2, 3);
    *(f16x4*)&Bs[la1 + 8] = __builtin_shufflevector(vb1, vb1, 4, 5, 6, 7);
    __syncthreads();
    f16x8 af[4], bfv[4];
#pragma unroll
    for (int m = 0; m < 4; ++m)
      af[m] = *(const f16x8*)&As[(wr * 64 + m * 16 + r16) * LDT + g * 8];
#pragma unroll
    for (int n = 0; n < 4; ++n)
      bfv[n] = *(const f16x8*)&Bs[(wc * 64 + n * 16 + r16) * LDT + g * 8];
#pragma unroll
    for (int m = 0; m < 4; ++m)
#pragma unroll
      for (int n = 0; n < 4; ++n)
        acc[m][n] = __builtin_amdgcn_mfma_f32_16x16x32_f16(af[m], bfv[n], acc[m][n], 0, 0, 0);
  }

  // C/D layout: col = lane&15, row = 4*(lane>>4) + reg
#pragma unroll
  for (int m = 0; m < 4; ++m) {
#pragma unroll
    for (int n = 0; n < 4; ++n) {
      const long row = bm + wr * 64 + m * 16 + g * 4;
      const int col = wc * 64 + n * 16 + r16;
      float bv = 0.f;
      if constexpr (PER_HEAD) bv = bias[col];
#pragma unroll
      for (int r = 0; r < 4; ++r) {
        float v = acc[m][n][r];
        if constexpr (PER_HEAD) {
          v += bv;
          v = v > 0.f ? v : (__expf(v) - 1.f);
        }
        C[(size_t)(row + r) * ldc + col] = (f16)v;
      }
    }
  }
}

// ---------------------------------------------------------------------------
// layer-1 aggregation in INPUT space: agg[d][h][:] = sum_e alpha_eh * x[src_e]
// (aggregation commutes with the W1 GEMM). Gathers 256B x-rows instead of
// 1KB h-rows. lane = (head g = lane>>4, r16 = lane&15 covering 8 cols each).
// Two-stage pipeline: src indices prefetched D edges ahead of the gathers.
// ---------------------------------------------------------------------------
__global__ __launch_bounds__(256) void aggregate1x(
    const f16* __restrict__ xsrc, const float* __restrict__ a_src,
    const float* __restrict__ a_dst, const int* __restrict__ rowstart,
    const int* __restrict__ csr, f16* __restrict__ aggb, int n) {
  const int wid0 = (blockIdx.x * blockDim.x + threadIdx.x) >> 6;
  if (wid0 >= M_PAD) return;
  const int wid = rfl(wid0);
  const int lane = threadIdx.x & 63;
  const int g = lane >> 4;
  const int col0 = (lane & 15) * 8;
  if (wid >= n) {  // zero the GEMM pad rows
    f16x8 z;
#pragma unroll
    for (int j = 0; j < 8; ++j) z[j] = (f16)0.f;
    *(f16x8*)&aggb[(size_t)wid * 512 + g * 128 + col0] = z;
    return;
  }
  const int rs = rfl(rowstart[wid]);
  const int re = rfl(rowstart[wid + 1]);
  const float adh = a_dst[(size_t)wid * 4 + g];

  constexpr int D = 6;
  int sreg[D];
  float areg[D];
  f16x8 hreg[D];
#pragma unroll
  for (int p = 0; p < D; ++p) {  // gathers for edges rs..rs+D-1
    const int k = rs + p;
    const int s = csr[(k < re) ? k : (re - 1)];
    areg[p] = a_src[(size_t)s * 4 + g];
    hreg[p] = *(const f16x8*)&xsrc[(size_t)s * 128 + col0];
  }
#pragma unroll
  for (int p = 0; p < D; ++p) {  // csr prefetch for edges rs+D..rs+2D-1
    const int k = rs + D + p;
    sreg[p] = csr[(k < re) ? k : (re - 1)];
  }

  float acc[8] = {};
  float Z = 0.f;
  for (int k = rs; k < re; k += D) {
#pragma unroll
    for (int p = 0; p < D; ++p) {
      const int cur = k + p;
      if (cur >= re) break;  // wave-uniform
      float e = areg[p] + adh;
      e = e > 0.f ? e : 0.2f * e;
      const float w = __expf(e);
      const f16x8 h = hreg[p];
      if (cur + D < re) {  // gather for edge cur+D with pre-fetched index
        const int s = sreg[p];
        areg[p] = a_src[(size_t)s * 4 + g];
        hreg[p] = *(const f16x8*)&xsrc[(size_t)s * 128 + col0];
      }
      if (cur + 2 * D < re) sreg[p] = csr[cur + 2 * D];
      Z += w;
#pragma unroll
      for (int j = 0; j < 8; ++j) acc[j] += w * (float)h[j];
    }
  }
  const float inv = 1.f / (Z + 1e-16f);
  f16x8 o;
#pragma unroll
  for (int j = 0; j < 8; ++j) o[j] = (f16)(acc[j] * inv);
  *(f16x8*)&aggb[(size_t)wid * 512 + g * 128 + col0] = o;
}

// ---------------------------------------------------------------------------
// a2[n] = out1[n] . V2   (out1 is f16)
// ---------------------------------------------------------------------------
__global__ __launch_bounds__(256) void a2_kernel(const f16* __restrict__ h,
                                                 const float* __restrict__ V2s,
                                                 const float* __restrict__ V2d,
                                                 float* __restrict__ as2,
                                                 float* __restrict__ ad2, int n) {
  const int wid = (blockIdx.x * blockDim.x + threadIdx.x) >> 6;
  const int lane = threadIdx.x & 63;
  if (wid >= n) return;
  const int k = lane * 8;
  f16x8 hv = *(const f16x8*)&h[(size_t)wid * 512 + k];
  float4 vsa = *(const float4*)&V2s[k];
  float4 vsb = *(const float4*)&V2s[k + 4];
  float4 vda = *(const float4*)&V2d[k];
  float4 vdb = *(const float4*)&V2d[k + 4];
  float s = (float)hv[0] * vsa.x + (float)hv[1] * vsa.y + (float)hv[2] * vsa.z +
            (float)hv[3] * vsa.w + (float)hv[4] * vsb.x + (float)hv[5] * vsb.y +
            (float)hv[6] * vsb.z + (float)hv[7] * vsb.w;
  float d = (float)hv[0] * vda.x + (float)hv[1] * vda.y + (float)hv[2] * vda.z +
            (float)hv[3] * vda.w + (float)hv[4] * vdb.x + (float)hv[5] * vdb.y +
            (float)hv[6] * vdb.z + (float)hv[7] * vdb.w;
#pragma unroll
  for (int off = 32; off; off >>= 1) {
    s += __shfl_xor(s, off);
    d += __shfl_xor(d, off);
  }
  if (lane == 0) { as2[wid] = s; ad2[wid] = d; }
}

// ---------------------------------------------------------------------------
// layer-2 aggregation (H=1, D=128): single-pass softmax, two-stage pipeline,
// fused bias+ELU+L2-normalize.  col0 = lane*2.
// ---------------------------------------------------------------------------
__global__ __launch_bounds__(256) void aggregate2(
    const f16* __restrict__ hsrc, const float* __restrict__ a_src,
    const float* __restrict__ a_dst, const int* __restrict__ rowstart,
    const int* __restrict__ csr, const float* __restrict__ bias,
    float* __restrict__ out, int n) {
  const int wid0 = (blockIdx.x * blockDim.x + threadIdx.x) >> 6;
  if (wid0 >= n) return;
  const int wid = rfl(wid0);
  const int lane = threadIdx.x & 63;
  const int col0 = lane * 2;
  const int rs = rfl(rowstart[wid]);
  const int re = rfl(rowstart[wid + 1]);
  const float ad = a_dst[wid];

  constexpr int D = 8;
  int sreg[D];
  float areg[D];
  f16x2 hreg[D];
#pragma unroll
  for (int p = 0; p < D; ++p) {
    const int k = rs + p;
    const int s = csr[(k < re) ? k : (re - 1)];
    areg[p] = a_src[s];
    hreg[p] = *(const f16x2*)&hsrc[(size_t)s * 128 + col0];
  }
#pragma unroll
  for (int p = 0; p < D; ++p) {
    const int k = rs + D + p;
    sreg[p] = csr[(k < re) ? k : (re - 1)];
  }

  float a0 = 0.f, a1 = 0.f, Z = 0.f;
  for (int k = rs; k < re; k += D) {
#pragma unroll
    for (int p = 0; p < D; ++p) {
      const int cur = k + p;
      if (cur >= re) break;  // wave-uniform
      float e = areg[p] + ad;
      e = e > 0.f ? e : 0.2f * e;
      const float w = __expf(e);
      const f16x2 h = hreg[p];
      if (cur + D < re) {
        const int s = sreg[p];
        areg[p] = a_src[s];
        hreg[p] = *(const f16x2*)&hsrc[(size_t)s * 128 + col0];
      }
      if (cur + 2 * D < re) sreg[p] = csr[cur + 2 * D];
      Z += w;
      a0 += w * (float)h[0];
      a1 += w * (float)h[1];
    }
  }
  const float inv = 1.f / (Z + 1e-16f);
  float v0 = a0 * inv + bias[col0], v1 = a1 * inv + bias[col0 + 1];
  v0 = v0 > 0.f ? v0 : (__expf(v0) - 1.f);
  v1 = v1 > 0.f ? v1 : (__expf(v1) - 1.f);
  float ss = v0 * v0 + v1 * v1;
#pragma unroll
  for (int off = 32; off; off >>= 1) ss += __shfl_xor(ss, off);
  const float invn = 1.f / fmaxf(sqrtf(ss), 1e-12f);
  float2 ov; ov.x = v0 * invn; ov.y = v1 * invn;
  *(float2*)&out[(size_t)wid * 128 + col0] = ov;
}

// ---------------------------------------------------------------------------
extern "C" void kernel_launch(void* const* d_in, const int* in_sizes, int n_in,
                              void* d_out, int out_size, void* d_ws, size_t ws_size,
                              hipStream_t stream) {
  const float* x        = (const float*)d_in[0];
  const int*   ei       = (const int*)d_in[1];
  const float* W1       = (const float*)d_in[2];
  const float* att_src1 = (const float*)d_in[3];
  const float* att_dst1 = (const float*)d_in[4];
  const float* bias1    = (const float*)d_in[5];
  const float* W2       = (const float*)d_in[6];
  const float* att_src2 = (const float*)d_in[7];
  const float* att_dst2 = (const float*)d_in[8];
  const float* bias2    = (const float*)d_in[9];
  float* out = (float*)d_out;

  char* ws = (char*)d_ws;
  size_t off = 0;
  auto alloc = [&](size_t bytes) {
    char* p = ws + off;
    off = (off + bytes + 255) & ~(size_t)255;
    return p;
  };
  f16* xb    = (f16*)alloc(sizeof(f16) * (size_t)M_PAD * 128);
  f16* w1t   = (f16*)alloc(sizeof(f16) * 512 * 128);
  f16* w2t   = (f16*)alloc(sizeof(f16) * 128 * 512);
  f16* aggb  = (f16*)alloc(sizeof(f16) * (size_t)M_PAD * 512);
  f16* out1b = (f16*)alloc(sizeof(f16) * (size_t)M_PAD * 512);
  float* V1s = (float*)alloc(sizeof(float) * 512);
  float* V1d = (float*)alloc(sizeof(float) * 512);
  float* V2s = (float*)alloc(sizeof(float) * 512);
  float* V2d = (float*)alloc(sizeof(float) * 512);
  float* as1 = (float*)alloc(sizeof(float) * N_NODES * 4);
  float* ad1 = (float*)alloc(sizeof(float) * N_NODES * 4);
  float* as2 = (float*)alloc(sizeof(float) * N_NODES);
  float* ad2 = (float*)alloc(sizeof(float) * N_NODES);
  int* rowstart = (int*)alloc(sizeof(int) * (SCAN_PAD + 4));
  int* cursor   = (int*)alloc(sizeof(int) * SCAN_PAD);
  int* bsum     = (int*)alloc(sizeof(int) * 64);
  int* csr      = (int*)alloc(sizeof(int) * TOT_EDGES);
  f16* h2b = aggb;  // alias: aggb dead after the head-GEMMs

  const int wgrid  = (N_NODES * 64) / 256;  // 12500 blocks, 1 wave/node
  const int wgridP = (M_PAD * 64) / 256;    // 12512 blocks (covers pad rows)

  // CSR build
  zero_int<<<(SCAN_PAD + 255) / 256, 256, 0, stream>>>(cursor, SCAN_PAD);
  count_kernel<<<(TOT_EDGES + 255) / 256, 256, 0, stream>>>(ei, cursor);
  block_scan<<<49, 256, 0, stream>>>(cursor, rowstart, bsum);
  bsum_scan<<<1, 64, 0, stream>>>(bsum, 49);
  add_off<<<49, 256, 0, stream>>>(rowstart, bsum, cursor);
  fill_kernel<<<(TOT_EDGES + 255) / 256, 256, 0, stream>>>(ei, cursor, csr);

  // weights + attention projection vectors
  make_v1<<<128, 256, 0, stream>>>(W1, att_src1, att_dst1, V1s, V1d);
  make_v2<<<128, 256, 0, stream>>>(W2, att_src2, att_dst2, V2s, V2d);
  cvt_w_t<<<(512 * 128 + 255) / 256, 256, 0, stream>>>(W1, w1t, 128, 512);
  cvt_w_t<<<(512 * 128 + 255) / 256, 256, 0, stream>>>(W2, w2t, 512, 128);
  prep_x<<<wgridP, 256, 0, stream>>>(x, xb, V1s, V1d, as1, ad1);

  // layer 1: aggregate x in input space, then 4 per-head GEMMs (+bias+ELU)
  aggregate1x<<<wgridP, 256, 0, stream>>>(xb, as1, ad1, rowstart, csr, aggb, N_NODES);
  gemm_bt<128, true><<<dim3(M_PAD / 128, 4), 256, 0, stream>>>(
      aggb, 512, w1t, 128, out1b, 512, bias1);

  // layer 2
  a2_kernel<<<wgrid, 256, 0, stream>>>(out1b, V2s, V2d, as2, ad2, N_NODES);
  gemm_bt<512, false><<<dim3(M_PAD / 128, 1), 256, 0, stream>>>(
      out1b, 512, w2t, 512, h2b, 128, nullptr);
  aggregate2<<<wgrid, 256, 0, stream>>>(h2b, as2, ad2, rowstart, csr, bias2, out, N_NODES);
}

// Round 6
// 213.247 us; speedup vs baseline: 1.1452x; 1.1452x over previous
//
#include <hip/hip_runtime.h>
#include <cstddef>

#define N_NODES 50000
#define N_EDGES 400000
#define TOT_EDGES (N_EDGES + N_NODES)
#define M_PAD 50048    // 391 * 128  (GEMM row padding)
#define SCAN_PAD 50176 // 49 * 1024  (scan padding)

typedef _Float16 f16;
typedef __attribute__((ext_vector_type(8))) _Float16 f16x8;
typedef __attribute__((ext_vector_type(4))) _Float16 f16x4;
typedef __attribute__((ext_vector_type(2))) _Float16 f16x2;
typedef __attribute__((ext_vector_type(4))) float f32x4;

// ---------------------------------------------------------------------------
// CSR build (parallel scan version)
// ---------------------------------------------------------------------------
__global__ void zero_int(int* __restrict__ p, int n) {
  int i = blockIdx.x * blockDim.x + threadIdx.x;
  if (i < n) p[i] = 0;
}

__global__ void count_kernel(const int* __restrict__ ei, int* __restrict__ cnt) {
  int e = blockIdx.x * blockDim.x + threadIdx.x;
  if (e >= TOT_EDGES) return;
  int dst = (e < N_EDGES) ? ei[N_EDGES + e] : (e - N_EDGES);
  atomicAdd(&cnt[dst], 1);
}

__global__ __launch_bounds__(256) void block_scan(const int* __restrict__ cnt,
                                                  int* __restrict__ pre,
                                                  int* __restrict__ bsum) {
  __shared__ int wsum[4];
  const int t = threadIdx.x, lane = t & 63, w = t >> 6;
  const int base = blockIdx.x * 1024 + t * 4;
  int4 v = *(const int4*)&cnt[base];
  const int s = v.x + v.y + v.z + v.w;
  int x = s;
#pragma unroll
  for (int off = 1; off < 64; off <<= 1) {
    int y = __shfl_up(x, off);
    if (lane >= off) x += y;
  }
  if (lane == 63) wsum[w] = x;
  __syncthreads();
  int woff = 0;
  for (int j = 0; j < w; ++j) woff += wsum[j];
  const int ex = x - s + woff;  // exclusive prefix within block
  pre[base + 0] = ex;
  pre[base + 1] = ex + v.x;
  pre[base + 2] = ex + v.x + v.y;
  pre[base + 3] = ex + v.x + v.y + v.z;
  if (t == 255) bsum[blockIdx.x] = ex + s;
}

__global__ void bsum_scan(int* __restrict__ bsum, int nb) {
  const int lane = threadIdx.x;
  int v = (lane < nb) ? bsum[lane] : 0;
  int x = v;
#pragma unroll
  for (int off = 1; off < 64; off <<= 1) {
    int y = __shfl_up(x, off);
    if (lane >= off) x += y;
  }
  if (lane < nb) bsum[lane] = x - v;
}

__global__ __launch_bounds__(256) void add_off(int* __restrict__ pre,
                                               const int* __restrict__ boff,
                                               int* __restrict__ cursor) {
  const int base = blockIdx.x * 1024 + threadIdx.x * 4;
  const int off = boff[blockIdx.x];
  int4 v = *(const int4*)&pre[base];
  v.x += off; v.y += off; v.z += off; v.w += off;
  *(int4*)&pre[base] = v;
  *(int4*)&cursor[base] = v;
}

__global__ void fill_kernel(const int* __restrict__ ei, int* __restrict__ cursor,
                            int* __restrict__ csr_src) {
  int e = blockIdx.x * blockDim.x + threadIdx.x;
  if (e >= TOT_EDGES) return;
  int s, d;
  if (e < N_EDGES) { s = ei[e]; d = ei[N_EDGES + e]; }
  else             { s = d = e - N_EDGES; }
  int pos = atomicAdd(&cursor[d], 1);
  csr_src[pos] = s;
}

// ---------------------------------------------------------------------------
// prep_x: x(f32) -> xb(f16, M_PAD rows, zero-padded)  +  a1 = x . V1 (f32)
// ---------------------------------------------------------------------------
__global__ __launch_bounds__(256) void prep_x(const float* __restrict__ x,
                                              f16* __restrict__ xb,
                                              const float* __restrict__ V1s,
                                              const float* __restrict__ V1d,
                                              float* __restrict__ as1,
                                              float* __restrict__ ad1) {
  const int wid = (blockIdx.x * 256 + threadIdx.x) >> 6;
  const int lane = threadIdx.x & 63;
  if (wid >= M_PAD) return;
  const int k = lane * 2;
  if (wid >= N_NODES) {
    f16x2 z; z[0] = (f16)0.f; z[1] = (f16)0.f;
    *(f16x2*)&xb[(size_t)wid * 128 + k] = z;
    return;
  }
  float2 xv = *(const float2*)&x[(size_t)wid * 128 + k];
  f16x2 o; o[0] = (f16)xv.x; o[1] = (f16)xv.y;
  *(f16x2*)&xb[(size_t)wid * 128 + k] = o;

  float4 vs0 = *(const float4*)&V1s[k * 4];
  float4 vs1 = *(const float4*)&V1s[(k + 1) * 4];
  float4 vd0 = *(const float4*)&V1d[k * 4];
  float4 vd1 = *(const float4*)&V1d[(k + 1) * 4];
  float s[4], d[4];
  s[0] = xv.x * vs0.x + xv.y * vs1.x;
  s[1] = xv.x * vs0.y + xv.y * vs1.y;
  s[2] = xv.x * vs0.z + xv.y * vs1.z;
  s[3] = xv.x * vs0.w + xv.y * vs1.w;
  d[0] = xv.x * vd0.x + xv.y * vd1.x;
  d[1] = xv.x * vd0.y + xv.y * vd1.y;
  d[2] = xv.x * vd0.z + xv.y * vd1.z;
  d[3] = xv.x * vd0.w + xv.y * vd1.w;
#pragma unroll
  for (int h = 0; h < 4; ++h) {
#pragma unroll
    for (int off = 32; off; off >>= 1) {
      s[h] += __shfl_xor(s[h], off);
      d[h] += __shfl_xor(d[h], off);
    }
  }
  if (lane == 0) {
    *(float4*)&as1[(size_t)wid * 4] = make_float4(s[0], s[1], s[2], s[3]);
    *(float4*)&ad1[(size_t)wid * 4] = make_float4(d[0], d[1], d[2], d[3]);
  }
}

// ---------------------------------------------------------------------------
// merged weight prep: blocks 0-255 -> w1t, 256-511 -> w2t,
// 512-639 -> V1 (make_v1), 640-767 -> V2 (make_v2)
// ---------------------------------------------------------------------------
__global__ __launch_bounds__(256) void prep_weights(
    const float* __restrict__ W1, const float* __restrict__ W2,
    const float* __restrict__ att_s1, const float* __restrict__ att_d1,
    const float* __restrict__ att_s2, const float* __restrict__ att_d2,
    f16* __restrict__ w1t, f16* __restrict__ w2t,
    float* __restrict__ V1s, float* __restrict__ V1d,
    float* __restrict__ V2s, float* __restrict__ V2d) {
  const int b = blockIdx.x;
  if (b < 256) {  // W1[128][512] -> w1t[512][128]
    const int idx = b * 256 + threadIdx.x;
    const int cc = idx >> 7, rr = idx & 127;
    w1t[idx] = (f16)W1[(size_t)rr * 512 + cc];
  } else if (b < 512) {  // W2[512][128] -> w2t[128][512]
    const int idx = (b - 256) * 256 + threadIdx.x;
    const int cc = idx >> 9, rr = idx & 511;
    w2t[idx] = (f16)W2[(size_t)rr * 128 + cc];
  } else if (b < 640) {  // V1
    const int wid = (b - 512) * 4 + (threadIdx.x >> 6);  // 0..511
    const int lane = threadIdx.x & 63;
    const int k = wid >> 2, h = wid & 3;
    const float* wrow = W1 + (size_t)k * 512 + h * 128;
    float2 wv = *(const float2*)&wrow[lane * 2];
    float2 sv = *(const float2*)&att_s1[h * 128 + lane * 2];
    float2 dv = *(const float2*)&att_d1[h * 128 + lane * 2];
    float ps = wv.x * sv.x + wv.y * sv.y;
    float pd = wv.x * dv.x + wv.y * dv.y;
#pragma unroll
    for (int off = 32; off; off >>= 1) {
      ps += __shfl_xor(ps, off);
      pd += __shfl_xor(pd, off);
    }
    if (lane == 0) { V1s[k * 4 + h] = ps; V1d[k * 4 + h] = pd; }
  } else {  // V2
    const int wid = (b - 640) * 4 + (threadIdx.x >> 6);  // k = 0..511
    const int lane = threadIdx.x & 63;
    const float* wrow = W2 + (size_t)wid * 128;
    float2 wv = *(const float2*)&wrow[lane * 2];
    float2 sv = *(const float2*)&att_s2[lane * 2];
    float2 dv = *(const float2*)&att_d2[lane * 2];
    float ps = wv.x * sv.x + wv.y * sv.y;
    float pd = wv.x * dv.x + wv.y * dv.y;
#pragma unroll
    for (int off = 32; off; off >>= 1) {
      ps += __shfl_xor(ps, off);
      pd += __shfl_xor(pd, off);
    }
    if (lane == 0) { V2s[wid] = ps; V2d[wid] = pd; }
  }
}

// ---------------------------------------------------------------------------
// generalized MFMA GEMM (unchanged from round 5)
// ---------------------------------------------------------------------------
template <int K, bool PER_HEAD>
__global__ __launch_bounds__(256) void gemm_bt(const f16* __restrict__ A, int lda,
                                               const f16* __restrict__ Bt, int ldb,
                                               f16* __restrict__ C, int ldc,
                                               const float* __restrict__ bias) {
  if constexpr (PER_HEAD) {
    const int hh = blockIdx.y;
    A += (size_t)hh * 128;
    Bt += (size_t)hh * 128 * 128;
    C += (size_t)hh * 128;
    bias += hh * 128;
  }
  constexpr int LDT = 40;
  __shared__ __align__(16) f16 As[128 * LDT];
  __shared__ __align__(16) f16 Bs[128 * LDT];
  const int tid = threadIdx.x;
  const int lane = tid & 63;
  const int g = lane >> 4, r16 = lane & 15;
  const int w = tid >> 6, wr = w >> 1, wc = w & 1;
  const long bm = (long)blockIdx.x * 128;

  const int row0 = tid >> 2, h0 = tid & 3;
  const int p1 = (h0 & 1) * 16 + (h0 >> 1) * 4;
  const size_t ga0 = (size_t)(bm + row0) * lda + h0 * 8;
  const size_t ga1 = (size_t)(bm + row0 + 64) * lda + h0 * 8;
  const size_t gb0 = (size_t)row0 * ldb + h0 * 8;
  const size_t gb1 = (size_t)(row0 + 64) * ldb + h0 * 8;
  const int la0 = row0 * LDT + p1, la1 = (row0 + 64) * LDT + p1;

  f32x4 acc[4][4] = {};

  for (int k0 = 0; k0 < K; k0 += 32) {
    __syncthreads();
    f16x8 va0 = *(const f16x8*)&A[ga0 + k0];
    f16x8 va1 = *(const f16x8*)&A[ga1 + k0];
    f16x8 vb0 = *(const f16x8*)&Bt[gb0 + k0];
    f16x8 vb1 = *(const f16x8*)&Bt[gb1 + k0];
    *(f16x4*)&As[la0]     = __builtin_shufflevector(va0, va0, 0, 1, 2, 3);
    *(f16x4*)&As[la0 + 8] = __builtin_shufflevector(va0, va0, 4, 5, 6, 7);
    *(f16x4*)&As[la1]     = __builtin_shufflevector(va1, va1, 0, 1, 2, 3);
    *(f16x4*)&As[la1 + 8] = __builtin_shufflevector(va1, va1, 4, 5, 6, 7);
    *(f16x4*)&Bs[la0]     = __builtin_shufflevector(vb0, vb0, 0, 1, 2, 3);
    *(f16x4*)&Bs[la0 + 8] = __builtin_shufflevector(vb0, vb0, 4, 5, 6, 7);
    *(f16x4*)&Bs[la1]     = __builtin_shufflevector(vb1, vb1, 0, 1, 2, 3);
    *(f16x4*)&Bs[la1 + 8] = __builtin_shufflevector(vb1, vb1, 4, 5, 6, 7);
    __syncthreads();
    f16x8 af[4], bfv[4];
#pragma unroll
    for (int m = 0; m < 4; ++m)
      af[m] = *(const f16x8*)&As[(wr * 64 + m * 16 + r16) * LDT + g * 8];
#pragma unroll
    for (int n = 0; n < 4; ++n)
      bfv[n] = *(const f16x8*)&Bs[(wc * 64 + n * 16 + r16) * LDT + g * 8];
#pragma unroll
    for (int m = 0; m < 4; ++m)
#pragma unroll
      for (int n = 0; n < 4; ++n)
        acc[m][n] = __builtin_amdgcn_mfma_f32_16x16x32_f16(af[m], bfv[n], acc[m][n], 0, 0, 0);
  }

  // C/D layout: col = lane&15, row = 4*(lane>>4) + reg
#pragma unroll
  for (int m = 0; m < 4; ++m) {
#pragma unroll
    for (int n = 0; n < 4; ++n) {
      const long row = bm + wr * 64 + m * 16 + g * 4;
      const int col = wc * 64 + n * 16 + r16;
      float bv = 0.f;
      if constexpr (PER_HEAD) bv = bias[col];
#pragma unroll
      for (int r = 0; r < 4; ++r) {
        float v = acc[m][n][r];
        if constexpr (PER_HEAD) {
          v += bv;
          v = v > 0.f ? v : (__expf(v) - 1.f);
        }
        C[(size_t)(row + r) * ldc + col] = (f16)v;
      }
    }
  }
}

// ---------------------------------------------------------------------------
// layer-1 aggregation in input space, 4 NODES PER WAVE (16 lanes each).
// Group g16 = lane>>4 owns node wave*4+g16; lane l16 holds f16x8 of the row.
// Per edge: 4 head weights computed redundantly per lane (no cross-lane ops);
// inactive iterations contribute weight 0. D-deep rolling pipeline with
// csr indices prefetched a further D ahead.
// ---------------------------------------------------------------------------
__global__ __launch_bounds__(256) void aggregate1x(
    const f16* __restrict__ xsrc, const float* __restrict__ a_src,
    const float* __restrict__ a_dst, const int* __restrict__ rowstart,
    const int* __restrict__ csr, f16* __restrict__ aggb, int n) {
  const int wave = (blockIdx.x * blockDim.x + threadIdx.x) >> 6;
  const int lane = threadIdx.x & 63;
  const int g16 = lane >> 4, l16 = lane & 15;
  const int node = wave * 4 + g16;  // < M_PAD by grid construction
  const int col0 = l16 * 8;
  const int rs = rowstart[node];
  const int re = rowstart[node + 1];  // pad nodes: rs==re (deg 0)
  const int deg = re - rs;
  float4 adv = *(const float4*)&a_dst[(size_t)node * 4];  // pad: garbage, unused

  int maxdeg = deg;
  maxdeg = max(maxdeg, __shfl_xor(maxdeg, 16));
  maxdeg = max(maxdeg, __shfl_xor(maxdeg, 32));

  constexpr int D = 4;
  int sreg[D];
  float4 areg[D];
  f16x8 hreg[D];
#pragma unroll
  for (int p = 0; p < D; ++p) {
    const int k = rs + p;
    const int s = csr[(k < re) ? k : (re - 1)];  // re>=1 always
    areg[p] = *(const float4*)&a_src[(size_t)s * 4];
    hreg[p] = *(const f16x8*)&xsrc[(size_t)s * 128 + col0];
    const int k2 = rs + D + p;
    sreg[p] = csr[(k2 < re) ? k2 : (re - 1)];
  }

  float acc0[8] = {}, acc1[8] = {}, acc2[8] = {}, acc3[8] = {};
  float Z0 = 0.f, Z1 = 0.f, Z2 = 0.f, Z3 = 0.f;
  for (int base = 0; base < maxdeg; base += D) {
#pragma unroll
    for (int p = 0; p < D; ++p) {
      const int i = base + p;
      const bool act = i < deg;
      float4 av = areg[p];
      float e0 = av.x + adv.x; e0 = e0 > 0.f ? e0 : 0.2f * e0;
      float e1 = av.y + adv.y; e1 = e1 > 0.f ? e1 : 0.2f * e1;
      float e2 = av.z + adv.z; e2 = e2 > 0.f ? e2 : 0.2f * e2;
      float e3 = av.w + adv.w; e3 = e3 > 0.f ? e3 : 0.2f * e3;
      const float w0 = act ? __expf(e0) : 0.f;
      const float w1 = act ? __expf(e1) : 0.f;
      const float w2 = act ? __expf(e2) : 0.f;
      const float w3 = act ? __expf(e3) : 0.f;
      const f16x8 h = hreg[p];
      const int nk = rs + i + D;
      if (nk < re) {  // 16-lane-coherent predicate
        const int s = sreg[p];
        areg[p] = *(const float4*)&a_src[(size_t)s * 4];
        hreg[p] = *(const f16x8*)&xsrc[(size_t)s * 128 + col0];
      }
      const int nk2 = rs + i + 2 * D;
      if (nk2 < re) sreg[p] = csr[nk2];
      Z0 += w0; Z1 += w1; Z2 += w2; Z3 += w3;
#pragma unroll
      for (int j = 0; j < 8; ++j) {
        const float hv = (float)h[j];
        acc0[j] += w0 * hv;
        acc1[j] += w1 * hv;
        acc2[j] += w2 * hv;
        acc3[j] += w3 * hv;
      }
    }
  }

  const float i0 = 1.f / (Z0 + 1e-16f);
  const float i1 = 1.f / (Z1 + 1e-16f);
  const float i2 = 1.f / (Z2 + 1e-16f);
  const float i3 = 1.f / (Z3 + 1e-16f);
  f16* orow = aggb + (size_t)node * 512 + col0;
  f16x8 o0, o1, o2, o3;
#pragma unroll
  for (int j = 0; j < 8; ++j) {
    o0[j] = (f16)(acc0[j] * i0);
    o1[j] = (f16)(acc1[j] * i1);
    o2[j] = (f16)(acc2[j] * i2);
    o3[j] = (f16)(acc3[j] * i3);
  }
  *(f16x8*)&orow[0]   = o0;
  *(f16x8*)&orow[128] = o1;
  *(f16x8*)&orow[256] = o2;
  *(f16x8*)&orow[384] = o3;
}

// ---------------------------------------------------------------------------
// a2[n] = out1[n] . V2   (out1 is f16)
// ---------------------------------------------------------------------------
__global__ __launch_bounds__(256) void a2_kernel(const f16* __restrict__ h,
                                                 const float* __restrict__ V2s,
                                                 const float* __restrict__ V2d,
                                                 float* __restrict__ as2,
                                                 float* __restrict__ ad2, int n) {
  const int wid = (blockIdx.x * blockDim.x + threadIdx.x) >> 6;
  const int lane = threadIdx.x & 63;
  if (wid >= n) return;
  const int k = lane * 8;
  f16x8 hv = *(const f16x8*)&h[(size_t)wid * 512 + k];
  float4 vsa = *(const float4*)&V2s[k];
  float4 vsb = *(const float4*)&V2s[k + 4];
  float4 vda = *(const float4*)&V2d[k];
  float4 vdb = *(const float4*)&V2d[k + 4];
  float s = (float)hv[0] * vsa.x + (float)hv[1] * vsa.y + (float)hv[2] * vsa.z +
            (float)hv[3] * vsa.w + (float)hv[4] * vsb.x + (float)hv[5] * vsb.y +
            (float)hv[6] * vsb.z + (float)hv[7] * vsb.w;
  float d = (float)hv[0] * vda.x + (float)hv[1] * vda.y + (float)hv[2] * vda.z +
            (float)hv[3] * vda.w + (float)hv[4] * vdb.x + (float)hv[5] * vdb.y +
            (float)hv[6] * vdb.z + (float)hv[7] * vdb.w;
#pragma unroll
  for (int off = 32; off; off >>= 1) {
    s += __shfl_xor(s, off);
    d += __shfl_xor(d, off);
  }
  if (lane == 0) { as2[wid] = s; ad2[wid] = d; }
}

// ---------------------------------------------------------------------------
// layer-2 aggregation, 4 NODES PER WAVE (16 lanes each), f16x8 row slices,
// single-pass softmax + fused bias/ELU/L2-normalize.
// ---------------------------------------------------------------------------
__global__ __launch_bounds__(256) void aggregate2(
    const f16* __restrict__ hsrc, const float* __restrict__ a_src,
    const float* __restrict__ a_dst, const int* __restrict__ rowstart,
    const int* __restrict__ csr, const float* __restrict__ bias,
    float* __restrict__ out, int n) {
  const int wave = (blockIdx.x * blockDim.x + threadIdx.x) >> 6;
  const int lane = threadIdx.x & 63;
  const int g16 = lane >> 4, l16 = lane & 15;
  const int node = wave * 4 + g16;  // < n exactly by grid construction
  const int col0 = l16 * 8;
  const int rs = rowstart[node];
  const int re = rowstart[node + 1];
  const int deg = re - rs;
  const float ad = a_dst[node];

  int maxdeg = deg;
  maxdeg = max(maxdeg, __shfl_xor(maxdeg, 16));
  maxdeg = max(maxdeg, __shfl_xor(maxdeg, 32));

  constexpr int D = 6;
  int sreg[D];
  float areg[D];
  f16x8 hreg[D];
#pragma unroll
  for (int p = 0; p < D; ++p) {
    const int k = rs + p;
    const int s = csr[(k < re) ? k : (re - 1)];
    areg[p] = a_src[s];
    hreg[p] = *(const f16x8*)&hsrc[(size_t)s * 128 + col0];
    const int k2 = rs + D + p;
    sreg[p] = csr[(k2 < re) ? k2 : (re - 1)];
  }

  float acc[8] = {};
  float Z = 0.f;
  for (int base = 0; base < maxdeg; base += D) {
#pragma unroll
    for (int p = 0; p < D; ++p) {
      const int i = base + p;
      const bool act = i < deg;
      float e = areg[p] + ad;
      e = e > 0.f ? e : 0.2f * e;
      const float w = act ? __expf(e) : 0.f;
      const f16x8 h = hreg[p];
      const int nk = rs + i + D;
      if (nk < re) {
        const int s = sreg[p];
        areg[p] = a_src[s];
        hreg[p] = *(const f16x8*)&hsrc[(size_t)s * 128 + col0];
      }
      const int nk2 = rs + i + 2 * D;
      if (nk2 < re) sreg[p] = csr[nk2];
      Z += w;
#pragma unroll
      for (int j = 0; j < 8; ++j) acc[j] += w * (float)h[j];
    }
  }
  const float inv = 1.f / (Z + 1e-16f);

  float4 ba = *(const float4*)&bias[col0];
  float4 bb = *(const float4*)&bias[col0 + 4];
  const float bv[8] = {ba.x, ba.y, ba.z, ba.w, bb.x, bb.y, bb.z, bb.w};
  float v[8];
  float ss = 0.f;
#pragma unroll
  for (int j = 0; j < 8; ++j) {
    float t = acc[j] * inv + bv[j];
    t = t > 0.f ? t : (__expf(t) - 1.f);
    v[j] = t;
    ss += t * t;
  }
  ss += __shfl_xor(ss, 1);
  ss += __shfl_xor(ss, 2);
  ss += __shfl_xor(ss, 4);
  ss += __shfl_xor(ss, 8);
  const float invn = 1.f / fmaxf(sqrtf(ss), 1e-12f);
  float* orow = out + (size_t)node * 128 + col0;
  float4 oa = make_float4(v[0] * invn, v[1] * invn, v[2] * invn, v[3] * invn);
  float4 ob = make_float4(v[4] * invn, v[5] * invn, v[6] * invn, v[7] * invn);
  *(float4*)&orow[0] = oa;
  *(float4*)&orow[4] = ob;
}

// ---------------------------------------------------------------------------
extern "C" void kernel_launch(void* const* d_in, const int* in_sizes, int n_in,
                              void* d_out, int out_size, void* d_ws, size_t ws_size,
                              hipStream_t stream) {
  const float* x        = (const float*)d_in[0];
  const int*   ei       = (const int*)d_in[1];
  const float* W1       = (const float*)d_in[2];
  const float* att_src1 = (const float*)d_in[3];
  const float* att_dst1 = (const float*)d_in[4];
  const float* bias1    = (const float*)d_in[5];
  const float* W2       = (const float*)d_in[6];
  const float* att_src2 = (const float*)d_in[7];
  const float* att_dst2 = (const float*)d_in[8];
  const float* bias2    = (const float*)d_in[9];
  float* out = (float*)d_out;

  char* ws = (char*)d_ws;
  size_t off = 0;
  auto alloc = [&](size_t bytes) {
    char* p = ws + off;
    off = (off + bytes + 255) & ~(size_t)255;
    return p;
  };
  f16* xb    = (f16*)alloc(sizeof(f16) * (size_t)M_PAD * 128);
  f16* w1t   = (f16*)alloc(sizeof(f16) * 512 * 128);
  f16* w2t   = (f16*)alloc(sizeof(f16) * 128 * 512);
  f16* aggb  = (f16*)alloc(sizeof(f16) * (size_t)M_PAD * 512);
  f16* out1b = (f16*)alloc(sizeof(f16) * (size_t)M_PAD * 512);
  float* V1s = (float*)alloc(sizeof(float) * 512);
  float* V1d = (float*)alloc(sizeof(float) * 512);
  float* V2s = (float*)alloc(sizeof(float) * 512);
  float* V2d = (float*)alloc(sizeof(float) * 512);
  float* as1 = (float*)alloc(sizeof(float) * N_NODES * 4);
  float* ad1 = (float*)alloc(sizeof(float) * N_NODES * 4);
  float* as2 = (float*)alloc(sizeof(float) * N_NODES);
  float* ad2 = (float*)alloc(sizeof(float) * N_NODES);
  int* rowstart = (int*)alloc(sizeof(int) * (SCAN_PAD + 4));
  int* cursor   = (int*)alloc(sizeof(int) * SCAN_PAD);
  int* bsum     = (int*)alloc(sizeof(int) * 64);
  int* csr      = (int*)alloc(sizeof(int) * TOT_EDGES);
  f16* h2b = aggb;  // alias: aggb dead after the head-GEMMs

  const int wgrid  = (N_NODES * 64) / 256;  // 1 wave/node kernels
  const int wgridP = (M_PAD * 64) / 256;

  // CSR build
  zero_int<<<(SCAN_PAD + 255) / 256, 256, 0, stream>>>(cursor, SCAN_PAD);
  count_kernel<<<(TOT_EDGES + 255) / 256, 256, 0, stream>>>(ei, cursor);
  block_scan<<<49, 256, 0, stream>>>(cursor, rowstart, bsum);
  bsum_scan<<<1, 64, 0, stream>>>(bsum, 49);
  add_off<<<49, 256, 0, stream>>>(rowstart, bsum, cursor);
  fill_kernel<<<(TOT_EDGES + 255) / 256, 256, 0, stream>>>(ei, cursor, csr);

  // weights + attention projection vectors (merged), then x prep
  prep_weights<<<768, 256, 0, stream>>>(W1, W2, att_src1, att_dst1,
                                        att_src2, att_dst2, w1t, w2t,
                                        V1s, V1d, V2s, V2d);
  prep_x<<<wgridP, 256, 0, stream>>>(x, xb, V1s, V1d, as1, ad1);

  // layer 1: aggregate x in input space (4 nodes/wave), then 4 head-GEMMs
  aggregate1x<<<(M_PAD / 4) * 64 / 256, 256, 0, stream>>>(
      xb, as1, ad1, rowstart, csr, aggb, N_NODES);
  gemm_bt<128, true><<<dim3(M_PAD / 128, 4), 256, 0, stream>>>(
      aggb, 512, w1t, 128, out1b, 512, bias1);

  // layer 2
  a2_kernel<<<wgrid, 256, 0, stream>>>(out1b, V2s, V2d, as2, ad2, N_NODES);
  gemm_bt<512, false><<<dim3(M_PAD / 128, 1), 256, 0, stream>>>(
      out1b, 512, w2t, 512, h2b, 128, nullptr);
  aggregate2<<<(N_NODES / 4) * 64 / 256, 256, 0, stream>>>(
      h2b, as2, ad2, rowstart, csr, bias2, out, N_NODES);
}